// Round 10
// baseline (293.032 us; speedup 1.0000x reference)
//
#include <hip/hip_runtime.h>
#include <hip/hip_fp16.h>

#define NN 50000
#define NE 800000
#define NB_SCAN 196   // ceil(NN/256)
#define NB_HIST 3125  // NE/256 exactly

typedef _Float16 f16x8 __attribute__((ext_vector_type(8)));
typedef float f32x4 __attribute__((ext_vector_type(4)));
union U4 { uint4 u; f16x8 f; __half2 h2[4]; };

__device__ inline f16x8 cvt8(float4 a0, float4 a1) {
  U4 u;
  u.h2[0] = __floats2half2_rn(a0.x, a0.y);
  u.h2[1] = __floats2half2_rn(a0.z, a0.w);
  u.h2[2] = __floats2half2_rn(a1.x, a1.y);
  u.h2[3] = __floats2half2_rn(a1.z, a1.w);
  return u.f;
}

// ---- workspace layout (4B units), 227*NN floats ----
// deg i32[NN]@0 | agg_h0[2NN]@NN | agg_e[32NN]@3NN | agg_h1 f32[64NN]@35NN
// h1h f16(32NN units)@99NN..131NN | W1t@131NN(2304), bsums@131NN+30000
// offs@132NN fill@133NN | eslist int2[NE] (32NN units)@134NN..166NN
// Pb f16@163NN..195NN, Qb f16@195NN..227NN
//   (Pb clobbers eslist tail, which is dead after gathers; Qb ends at 227NN)

// ---------------- CSR hist (+ folded W1 transpose) --------------------------
__global__ __launch_bounds__(256) void k_hist(const int* __restrict__ ei,
                                              int* __restrict__ deg,
                                              const float* __restrict__ W1,
                                              float* __restrict__ W1t) {
  if (blockIdx.x >= NB_HIST) {
    int id = (blockIdx.x - NB_HIST) * 256 + threadIdx.x;
    if (id < 36 * 64) {
      int k = id >> 6, o = id & 63;
      W1t[id] = W1[o * 36 + k];
    }
    return;
  }
  int e = blockIdx.x * 256 + threadIdx.x;
  atomicAdd(&deg[ei[NE + e]], 1);
}

__global__ __launch_bounds__(256) void k_scan1(const int* __restrict__ deg,
                                               int* __restrict__ offs,
                                               int* __restrict__ bsums) {
  __shared__ int sh[256];
  int tid = threadIdx.x;
  int i = blockIdx.x * 256 + tid;
  int v = (i < NN) ? deg[i] : 0;
  int val = v;
  sh[tid] = val;
  __syncthreads();
  for (int ofs = 1; ofs < 256; ofs <<= 1) {
    int t = (tid >= ofs) ? sh[tid - ofs] : 0;
    __syncthreads();
    val += t;
    sh[tid] = val;
    __syncthreads();
  }
  if (i < NN) offs[i] = val - v;
  if (tid == 255) bsums[blockIdx.x] = val;
}

__global__ __launch_bounds__(256) void k_scan2(int* __restrict__ bsums) {
  __shared__ int sh[256];
  int tid = threadIdx.x;
  int v = (tid < NB_SCAN) ? bsums[tid] : 0;
  int val = v;
  sh[tid] = val;
  __syncthreads();
  for (int ofs = 1; ofs < 256; ofs <<= 1) {
    int t = (tid >= ofs) ? sh[tid - ofs] : 0;
    __syncthreads();
    val += t;
    sh[tid] = val;
    __syncthreads();
  }
  if (tid < NB_SCAN) bsums[tid] = val - v;
}

// offs += block base; fill seeded with the final offset (scatter uses fill only)
__global__ __launch_bounds__(256) void k_scan3(int* __restrict__ offs,
                                               const int* __restrict__ bsums,
                                               int* __restrict__ fill) {
  int i = blockIdx.x * 256 + threadIdx.x;
  if (i < NN) {
    int v = offs[i] + bsums[blockIdx.x];
    offs[i] = v;
    fill[i] = v;
  }
}

__global__ __launch_bounds__(256) void k_scatter(const int* __restrict__ ei,
                                                 int* __restrict__ fill,
                                                 int2* __restrict__ eslist) {
  int e = blockIdx.x * 256 + threadIdx.x;
  if (e >= NE) return;
  int s = ei[e];
  int d = ei[NE + e];
  int pos = atomicAdd(&fill[d], 1);
  eslist[pos] = make_int2(e, s);
}

// ---------------- gather0: 32 lanes/node, 8-edge unroll ---------------------
__global__ __launch_bounds__(256) void k_gather0(
    const float* __restrict__ ea, const float* __restrict__ ns,
    const int* __restrict__ offs, const int* __restrict__ deg,
    const int2* __restrict__ eslist, float* __restrict__ agg_h0,
    float* __restrict__ agg_e) {
  int idx = blockIdx.x * 256 + threadIdx.x;
  int n = idx >> 5, k = idx & 31;
  if (n >= NN) return;
  int off = offs[n], dg = deg[n];
  float a0 = 0.f, a1 = 0.f, a2 = 0.f, a3 = 0.f;
  float h0 = 0.f, h1v = 0.f;
  int i = 0;
  for (; i + 8 <= dg; i += 8) {
    int2 p0 = eslist[off + i + 0], p1 = eslist[off + i + 1];
    int2 p2 = eslist[off + i + 2], p3 = eslist[off + i + 3];
    int2 p4 = eslist[off + i + 4], p5 = eslist[off + i + 5];
    int2 p6 = eslist[off + i + 6], p7 = eslist[off + i + 7];
    a0 += ea[(size_t)p0.x * 32 + k];
    a1 += ea[(size_t)p1.x * 32 + k];
    a2 += ea[(size_t)p2.x * 32 + k];
    a3 += ea[(size_t)p3.x * 32 + k];
    a0 += ea[(size_t)p4.x * 32 + k];
    a1 += ea[(size_t)p5.x * 32 + k];
    a2 += ea[(size_t)p6.x * 32 + k];
    a3 += ea[(size_t)p7.x * 32 + k];
    if (k < 2) {
      h0 += ns[(size_t)p0.y * 2 + k] + ns[(size_t)p2.y * 2 + k];
      h1v += ns[(size_t)p1.y * 2 + k] + ns[(size_t)p3.y * 2 + k];
      h0 += ns[(size_t)p4.y * 2 + k] + ns[(size_t)p6.y * 2 + k];
      h1v += ns[(size_t)p5.y * 2 + k] + ns[(size_t)p7.y * 2 + k];
    }
  }
  for (; i + 2 <= dg; i += 2) {
    int2 p0 = eslist[off + i], p1 = eslist[off + i + 1];
    a0 += ea[(size_t)p0.x * 32 + k];
    a1 += ea[(size_t)p1.x * 32 + k];
    if (k < 2) {
      h0 += ns[(size_t)p0.y * 2 + k];
      h1v += ns[(size_t)p1.y * 2 + k];
    }
  }
  if (i < dg) {
    int2 p0 = eslist[off + i];
    a0 += ea[(size_t)p0.x * 32 + k];
    if (k < 2) h0 += ns[(size_t)p0.y * 2 + k];
  }
  agg_e[(size_t)n * 32 + k] = (a0 + a1) + (a2 + a3);
  if (k < 2) agg_h0[(size_t)n * 2 + k] = h0 + h1v;
}

// ---------------- gather1: wave/node, 8-row unroll --------------------------
__global__ __launch_bounds__(256) void k_gather1(
    const __half* __restrict__ h1h, const int* __restrict__ offs,
    const int* __restrict__ deg, const int2* __restrict__ eslist,
    float* __restrict__ agg_h1) {
  int idx = blockIdx.x * 256 + threadIdx.x;
  int n = idx >> 6, lane = idx & 63;
  if (n >= NN) return;
  int off = offs[n], dg = deg[n];
  float a0 = 0.f, a1 = 0.f, a2 = 0.f, a3 = 0.f;
  int i = 0;
  for (; i + 8 <= dg; i += 8) {
    int s0 = eslist[off + i + 0].y, s1 = eslist[off + i + 1].y;
    int s2 = eslist[off + i + 2].y, s3 = eslist[off + i + 3].y;
    int s4 = eslist[off + i + 4].y, s5 = eslist[off + i + 5].y;
    int s6 = eslist[off + i + 6].y, s7 = eslist[off + i + 7].y;
    a0 += __half2float(h1h[(size_t)s0 * 64 + lane]);
    a1 += __half2float(h1h[(size_t)s1 * 64 + lane]);
    a2 += __half2float(h1h[(size_t)s2 * 64 + lane]);
    a3 += __half2float(h1h[(size_t)s3 * 64 + lane]);
    a0 += __half2float(h1h[(size_t)s4 * 64 + lane]);
    a1 += __half2float(h1h[(size_t)s5 * 64 + lane]);
    a2 += __half2float(h1h[(size_t)s6 * 64 + lane]);
    a3 += __half2float(h1h[(size_t)s7 * 64 + lane]);
  }
  for (; i + 2 <= dg; i += 2) {
    int s0 = eslist[off + i].y, s1 = eslist[off + i + 1].y;
    a0 += __half2float(h1h[(size_t)s0 * 64 + lane]);
    a1 += __half2float(h1h[(size_t)s1 * 64 + lane]);
  }
  if (i < dg) a0 += __half2float(h1h[(size_t)eslist[off + i].y * 64 + lane]);
  agg_h1[(size_t)n * 64 + lane] = (a0 + a1) + (a2 + a3);
}

// ---------------- node linear 1 (vector; K=36) ------------------------------
__global__ __launch_bounds__(256) void k_node_lin1(
    const float* __restrict__ ns, const int* __restrict__ deg,
    const float* __restrict__ agg_h0, const float* __restrict__ agg_e,
    const float* __restrict__ W1t, const float* __restrict__ b1,
    __half* __restrict__ h1h) {
  int idx = blockIdx.x * 256 + threadIdx.x;
  int n = idx >> 6, o = idx & 63;
  if (n >= NN) return;
  float inv = 1.0f / fmaxf((float)deg[n], 1.0f);
  float acc = b1[o], acc2 = 0.f;
  acc += ns[n * 2 + 0] * W1t[0 * 64 + o] + ns[n * 2 + 1] * W1t[1 * 64 + o];
  acc2 += agg_h0[n * 2 + 0] * inv * W1t[2 * 64 + o] +
          agg_h0[n * 2 + 1] * inv * W1t[3 * 64 + o];
#pragma unroll
  for (int k = 0; k < 32; k += 2) {
    acc += agg_e[n * 32 + k] * inv * W1t[(4 + k) * 64 + o];
    acc2 += agg_e[n * 32 + k + 1] * inv * W1t[(5 + k) * 64 + o];
  }
  h1h[n * 64 + o] = __float2half(fmaxf(acc + acc2, 0.0f));
}

// ---------------- fused lin2 + pq: MFMA, 16-node tile per wave --------------
__global__ __launch_bounds__(256) void k_lin2pq(
    const __half* __restrict__ h1h, const int* __restrict__ deg,
    const float* __restrict__ agg_h1, const float* __restrict__ agg_e,
    const float* __restrict__ W2, const float* __restrict__ b2,
    const float* __restrict__ Wc1, const float* __restrict__ bc1,
    __half* __restrict__ Pb, __half* __restrict__ Qb) {
  __shared__ float Zt[4][16 * 68];
  int tid = threadIdx.x, lane = tid & 63, wid = tid >> 6;
  int col = lane & 15, quad = lane >> 4;
  float* zl = &Zt[wid][0];
  int task = blockIdx.x * 4 + wid;
  if (task >= NN / 16) return;  // NN = 3125*16 exactly
  int nb = task * 16;
  int nrow = nb + col;
  float inv = 1.0f / fmaxf((float)deg[nrow], 1.0f);

  f32x4 zero = {0.f, 0.f, 0.f, 0.f};
  f32x4 ce[4] = {zero, zero, zero, zero};

#pragma unroll
  for (int kc = 0; kc < 5; ++kc) {
    f16x8 af;
    if (kc < 2) {
      U4 u;
      u.u = *(const uint4*)(h1h + (size_t)nrow * 64 + kc * 32 + quad * 8);
      af = u.f;
    } else if (kc < 4) {
      const float* p = agg_h1 + (size_t)nrow * 64 + (kc - 2) * 32 + quad * 8;
      float4 a0 = ((const float4*)p)[0], a1 = ((const float4*)p)[1];
      a0.x *= inv; a0.y *= inv; a0.z *= inv; a0.w *= inv;
      a1.x *= inv; a1.y *= inv; a1.z *= inv; a1.w *= inv;
      af = cvt8(a0, a1);
    } else {
      const float* p = agg_e + (size_t)nrow * 32 + quad * 8;
      float4 a0 = ((const float4*)p)[0], a1 = ((const float4*)p)[1];
      a0.x *= inv; a0.y *= inv; a0.z *= inv; a0.w *= inv;
      a1.x *= inv; a1.y *= inv; a1.z *= inv; a1.w *= inv;
      af = cvt8(a0, a1);
    }
#pragma unroll
    for (int ob = 0; ob < 4; ++ob) {
      const float* wp = W2 + (size_t)(ob * 16 + col) * 160 + kc * 32 + quad * 8;
      f16x8 bf = cvt8(((const float4*)wp)[0], ((const float4*)wp)[1]);
      ce[ob] = __builtin_amdgcn_mfma_f32_16x16x32_f16(af, bf, ce[ob], 0, 0, 0);
    }
  }
#pragma unroll
  for (int ob = 0; ob < 4; ++ob) {
    float bv = b2[ob * 16 + col];
#pragma unroll
    for (int j = 0; j < 4; ++j)
      zl[(quad * 4 + j) * 68 + ob * 16 + col] = fmaxf(ce[ob][j] + bv, 0.f);
  }

  f32x4 pacc[4] = {zero, zero, zero, zero};
  f32x4 qacc[4] = {zero, zero, zero, zero};
#pragma unroll
  for (int kc = 0; kc < 2; ++kc) {
    const float* zc = zl + col * 68 + kc * 32 + quad * 8;
    f16x8 az = cvt8(((const float4*)zc)[0], ((const float4*)zc)[1]);
#pragma unroll
    for (int ob = 0; ob < 4; ++ob) {
      const float* wa = Wc1 + (size_t)(ob * 16 + col) * 160 + kc * 32 + quad * 8;
      f16x8 ba = cvt8(((const float4*)wa)[0], ((const float4*)wa)[1]);
      pacc[ob] = __builtin_amdgcn_mfma_f32_16x16x32_f16(az, ba, pacc[ob], 0, 0, 0);
      const float* wb = wa + 64;
      f16x8 bb = cvt8(((const float4*)wb)[0], ((const float4*)wb)[1]);
      qacc[ob] = __builtin_amdgcn_mfma_f32_16x16x32_f16(az, bb, qacc[ob], 0, 0, 0);
    }
  }
#pragma unroll
  for (int ob = 0; ob < 4; ++ob) {
    float bv = bc1[ob * 16 + col];
#pragma unroll
    for (int j = 0; j < 4; ++j) {
      int n = nb + quad * 4 + j;
      Pb[(size_t)n * 64 + ob * 16 + col] = __float2half(pacc[ob][j] + bv);
      Qb[(size_t)n * 64 + ob * 16 + col] = __float2half(qacc[ob][j]);
    }
  }
}

// ---------------- edge classifier: MFMA, 4 blocks/CU, dbuf Zt ---------------
#define CLS_BLOCKS 3125  // 12500 waves, 1 task (64 edges) each
__global__ __launch_bounds__(256, 4) void k_edge_cls(
    const int* __restrict__ ei, const float* __restrict__ ea,
    const __half* __restrict__ Pb, const __half* __restrict__ Qb,
    const float* __restrict__ Wc1, const float* __restrict__ Wc2,
    const float* __restrict__ bc2, const float* __restrict__ Wc3,
    const float* __restrict__ bc3, float* __restrict__ out) {
  __shared__ float Zt[4][2][16 * 68];  // dbuf: no LDS-reuse ordering across mt
  int tid = threadIdx.x;
  int lane = tid & 63, wid = tid >> 6;
  int col = lane & 15, quad = lane >> 4;

  f16x8 ctF[4];
#pragma unroll
  for (int nt = 0; nt < 4; ++nt) {
    const float* p = Wc1 + (nt * 16 + col) * 160 + 128 + quad * 8;
    ctF[nt] = cvt8(((const float4*)p)[0], ((const float4*)p)[1]);
  }
  f16x8 w2F[2][2];
#pragma unroll
  for (int nt = 0; nt < 2; ++nt)
#pragma unroll
    for (int ks = 0; ks < 2; ++ks) {
      const float* p = Wc2 + (nt * 16 + col) * 64 + ks * 32 + quad * 8;
      w2F[nt][ks] = cvt8(((const float4*)p)[0], ((const float4*)p)[1]);
    }
  float wc3v0 = Wc3[col], wc3v1 = Wc3[16 + col];
  float bc2v0 = bc2[col], bc2v1 = bc2[16 + col];
  float bc3v = bc3[0];

  int gw = blockIdx.x * 4 + wid;
  for (int task = gw; task < NE / 64; task += CLS_BLOCKS * 4) {
    int tb = task * 64;
    // hoist all 4 tiles' edge-index loads: 8 independent loads in flight
    int sArr[4], dArr[4];
#pragma unroll
    for (int mt = 0; mt < 4; ++mt) {
      sArr[mt] = ei[tb + mt * 16 + col];
      dArr[mt] = ei[NE + tb + mt * 16 + col];
    }
#pragma unroll
    for (int mt = 0; mt < 4; ++mt) {
      int eb = tb + mt * 16;
      int e = eb + col;
      int s = sArr[mt], d = dArr[mt];
      float* zl = &Zt[wid][mt & 1][0];

      const float* eap = ea + (size_t)e * 32 + quad * 8;
      f16x8 ua = cvt8(((const float4*)eap)[0], ((const float4*)eap)[1]);
      f32x4 zero = {0.f, 0.f, 0.f, 0.f};
      f32x4 ce[4];
#pragma unroll
      for (int nt = 0; nt < 4; ++nt)
        ce[nt] = __builtin_amdgcn_mfma_f32_16x16x32_f16(ua, ctF[nt], zero,
                                                        0, 0, 0);
#pragma unroll
      for (int nt = 0; nt < 4; ++nt)
#pragma unroll
        for (int j = 0; j < 4; ++j)
          zl[(quad * 4 + j) * 68 + nt * 16 + col] = ce[nt][j];

      const __half* prow = Pb + (size_t)s * 64 + quad * 8;
      const __half* qrow = Qb + (size_t)d * 64 + quad * 8;
      f32x4 tacc0 = zero, tacc1 = zero;
#pragma unroll
      for (int ks = 0; ks < 2; ++ks) {
        U4 up, uq;
        up.u = *(const uint4*)(prow + ks * 32);
        uq.u = *(const uint4*)(qrow + ks * 32);
        const float* zc = zl + col * 68 + ks * 32 + quad * 8;
        float4 c0 = *(const float4*)(zc);
        float4 c1 = *(const float4*)(zc + 4);
        U4 uz;
        {
          float2 pf, qf;
          pf = __half22float2(up.h2[0]); qf = __half22float2(uq.h2[0]);
          uz.h2[0] = __floats2half2_rn(fmaxf(pf.x + qf.x + c0.x, 0.f),
                                       fmaxf(pf.y + qf.y + c0.y, 0.f));
          pf = __half22float2(up.h2[1]); qf = __half22float2(uq.h2[1]);
          uz.h2[1] = __floats2half2_rn(fmaxf(pf.x + qf.x + c0.z, 0.f),
                                       fmaxf(pf.y + qf.y + c0.w, 0.f));
          pf = __half22float2(up.h2[2]); qf = __half22float2(uq.h2[2]);
          uz.h2[2] = __floats2half2_rn(fmaxf(pf.x + qf.x + c1.x, 0.f),
                                       fmaxf(pf.y + qf.y + c1.y, 0.f));
          pf = __half22float2(up.h2[3]); qf = __half22float2(uq.h2[3]);
          uz.h2[3] = __floats2half2_rn(fmaxf(pf.x + qf.x + c1.z, 0.f),
                                       fmaxf(pf.y + qf.y + c1.w, 0.f));
        }
        tacc0 = __builtin_amdgcn_mfma_f32_16x16x32_f16(uz.f, w2F[0][ks],
                                                       tacc0, 0, 0, 0);
        tacc1 = __builtin_amdgcn_mfma_f32_16x16x32_f16(uz.f, w2F[1][ks],
                                                       tacc1, 0, 0, 0);
      }

      float vj[4];
#pragma unroll
      for (int j = 0; j < 4; ++j) {
        float t0 = fmaxf(tacc0[j] + bc2v0, 0.f);
        float t1 = fmaxf(tacc1[j] + bc2v1, 0.f);
        vj[j] = t0 * wc3v0 + t1 * wc3v1;
      }
#pragma unroll
      for (int m = 1; m < 16; m <<= 1) {
#pragma unroll
        for (int j = 0; j < 4; ++j) vj[j] += __shfl_xor(vj[j], m);
      }
      if (col == 0) {
#pragma unroll
        for (int j = 0; j < 4; ++j) out[eb + quad * 4 + j] = vj[j] + bc3v;
      }
    }
  }
}

extern "C" void kernel_launch(void* const* d_in, const int* in_sizes, int n_in,
                              void* d_out, int out_size, void* d_ws, size_t ws_size,
                              hipStream_t stream) {
  const int*   ei  = (const int*)d_in[1];
  const float* ea  = (const float*)d_in[2];
  const float* ns  = (const float*)d_in[3];
  const float* W1  = (const float*)d_in[4];
  const float* b1  = (const float*)d_in[5];
  const float* W2  = (const float*)d_in[6];
  const float* b2  = (const float*)d_in[7];
  const float* Wc1 = (const float*)d_in[8];
  const float* bc1 = (const float*)d_in[9];
  const float* Wc2 = (const float*)d_in[10];
  const float* bc2 = (const float*)d_in[11];
  const float* Wc3 = (const float*)d_in[12];
  const float* bc3 = (const float*)d_in[13];
  float* out = (float*)d_out;

  float*  ws     = (float*)d_ws;
  int*    deg    = (int*)ws;
  float*  agg_h0 = ws + (size_t)NN;
  float*  agg_e  = ws + (size_t)3 * NN;
  float*  agg_h1 = ws + (size_t)35 * NN;
  __half* h1h    = (__half*)(ws + (size_t)99 * NN);
  float*  W1t    = ws + (size_t)131 * NN;
  int*    bsums  = (int*)(W1t + 30000);
  int*    offs   = (int*)(ws + (size_t)132 * NN);
  int*    fill   = (int*)(ws + (size_t)133 * NN);
  int2*   eslist = (int2*)(ws + (size_t)134 * NN);   // 32NN units -> 166NN
  __half* Pb     = (__half*)(ws + (size_t)163 * NN); // clobbers eslist tail
  __half* Qb     = (__half*)(ws + (size_t)195 * NN); // ends at 227NN

  hipMemsetAsync(deg, 0, NN * sizeof(int), stream);

  k_hist<<<NB_HIST + 9, 256, 0, stream>>>(ei, deg, W1, W1t);
  k_scan1<<<NB_SCAN, 256, 0, stream>>>(deg, offs, bsums);
  k_scan2<<<1, 256, 0, stream>>>(bsums);
  k_scan3<<<NB_SCAN, 256, 0, stream>>>(offs, bsums, fill);
  k_scatter<<<NB_HIST, 256, 0, stream>>>(ei, fill, eslist);

  k_gather0<<<(NN * 32 + 255) / 256, 256, 0, stream>>>(ea, ns, offs, deg,
                                                       eslist, agg_h0, agg_e);
  k_node_lin1<<<(NN * 64 + 255) / 256, 256, 0, stream>>>(ns, deg, agg_h0,
                                                         agg_e, W1t, b1, h1h);
  k_gather1<<<(NN * 64 + 255) / 256, 256, 0, stream>>>(h1h, offs, deg, eslist,
                                                       agg_h1);
  k_lin2pq<<<(NN / 16 + 3) / 4, 256, 0, stream>>>(h1h, deg, agg_h1, agg_e, W2,
                                                  b2, Wc1, bc1, Pb, Qb);
  k_edge_cls<<<CLS_BLOCKS, 256, 0, stream>>>(ei, ea, Pb, Qb, Wc1, Wc2, bc2,
                                             Wc3, bc3, out);
}

// Round 11
// 285.356 us; speedup vs baseline: 1.0269x; 1.0269x over previous
//
#include <hip/hip_runtime.h>
#include <hip/hip_fp16.h>

#define NN 50000
#define NE 800000
#define NB_SCAN 196   // ceil(NN/256)
#define NB_HIST 3125  // NE/256 exactly

typedef _Float16 f16x8 __attribute__((ext_vector_type(8)));
typedef float f32x4 __attribute__((ext_vector_type(4)));
typedef unsigned long long u64;
union U4 { uint4 u; f16x8 f; __half2 h2[4]; };

__device__ inline f16x8 cvt8(float4 a0, float4 a1) {
  U4 u;
  u.h2[0] = __floats2half2_rn(a0.x, a0.y);
  u.h2[1] = __floats2half2_rn(a0.z, a0.w);
  u.h2[2] = __floats2half2_rn(a1.x, a1.y);
  u.h2[3] = __floats2half2_rn(a1.z, a1.w);
  return u.f;
}

// CSR slot encoding: e (20b) | s<<20 (17b) | d<<40 (17b)
__device__ inline int dec_e(u64 v) { return (int)(v & 0xFFFFFull); }
__device__ inline int dec_s(u64 v) { return (int)((v >> 20) & 0x1FFFFull); }
__device__ inline int dec_d(u64 v) { return (int)(v >> 40); }

// ---- workspace layout (4B units), 227*NN floats ----
// deg i32[NN]@0 | agg_h0[2NN]@NN | agg_e[32NN]@3NN | agg_h1 f32[64NN]@35NN
// h1h f16(32NN units)@99NN..131NN | W1t@131NN(2304), bsums@131NN+30000
// offs@132NN fill@133NN | eslist u64[NE] (32NN units)@134NN..166NN
// Pb f16@163NN..195NN, Qb f16@195NN..227NN
//   (Pb clobbers eslist tail only AFTER lin2pq; eslist still read by cls —
//    tail edges 725K..800K! -> keep eslist fully alive: move it to 134NN and
//    note Pb/Qb overlap: Pb@163NN overlaps eslist[29NN..32NN units].
//    NOT OK for CSR-cls. Fix: eslist @131NN+4096.. no. See launch: eslist
//    relocated to 99NN? h1h dead after lin2pq but eslist written before...
//    Resolution used here: Pb/Qb live in agg_e/agg_h1 region instead:
//    Pb f16(32NN)@3NN (over agg_e, dead after lin2pq)
//    Qb f16(32NN)@35NN (over agg_h1 first half, dead after lin2pq)
//    eslist stays @134NN..166NN, untouched until end of cls.

// ---------------- CSR hist (+ folded W1 transpose) --------------------------
__global__ __launch_bounds__(256) void k_hist(const int* __restrict__ ei,
                                              int* __restrict__ deg,
                                              const float* __restrict__ W1,
                                              float* __restrict__ W1t) {
  if (blockIdx.x >= NB_HIST) {
    int id = (blockIdx.x - NB_HIST) * 256 + threadIdx.x;
    if (id < 36 * 64) {
      int k = id >> 6, o = id & 63;
      W1t[id] = W1[o * 36 + k];
    }
    return;
  }
  int e = blockIdx.x * 256 + threadIdx.x;
  atomicAdd(&deg[ei[NE + e]], 1);
}

__global__ __launch_bounds__(256) void k_scan1(const int* __restrict__ deg,
                                               int* __restrict__ offs,
                                               int* __restrict__ bsums) {
  __shared__ int sh[256];
  int tid = threadIdx.x;
  int i = blockIdx.x * 256 + tid;
  int v = (i < NN) ? deg[i] : 0;
  int val = v;
  sh[tid] = val;
  __syncthreads();
  for (int ofs = 1; ofs < 256; ofs <<= 1) {
    int t = (tid >= ofs) ? sh[tid - ofs] : 0;
    __syncthreads();
    val += t;
    sh[tid] = val;
    __syncthreads();
  }
  if (i < NN) offs[i] = val - v;
  if (tid == 255) bsums[blockIdx.x] = val;
}

__global__ __launch_bounds__(256) void k_scan2(int* __restrict__ bsums) {
  __shared__ int sh[256];
  int tid = threadIdx.x;
  int v = (tid < NB_SCAN) ? bsums[tid] : 0;
  int val = v;
  sh[tid] = val;
  __syncthreads();
  for (int ofs = 1; ofs < 256; ofs <<= 1) {
    int t = (tid >= ofs) ? sh[tid - ofs] : 0;
    __syncthreads();
    val += t;
    sh[tid] = val;
    __syncthreads();
  }
  if (tid < NB_SCAN) bsums[tid] = val - v;
}

__global__ __launch_bounds__(256) void k_scan3(int* __restrict__ offs,
                                               const int* __restrict__ bsums,
                                               int* __restrict__ fill) {
  int i = blockIdx.x * 256 + threadIdx.x;
  if (i < NN) {
    int v = offs[i] + bsums[blockIdx.x];
    offs[i] = v;
    fill[i] = v;
  }
}

__global__ __launch_bounds__(256) void k_scatter(const int* __restrict__ ei,
                                                 int* __restrict__ fill,
                                                 u64* __restrict__ eslist) {
  int e = blockIdx.x * 256 + threadIdx.x;
  if (e >= NE) return;
  int s = ei[e];
  int d = ei[NE + e];
  int pos = atomicAdd(&fill[d], 1);
  eslist[pos] = (u64)e | ((u64)s << 20) | ((u64)d << 40);
}

// ---------------- gather0: 32 lanes/node, 8-edge unroll ---------------------
__global__ __launch_bounds__(256) void k_gather0(
    const float* __restrict__ ea, const float* __restrict__ ns,
    const int* __restrict__ offs, const int* __restrict__ deg,
    const u64* __restrict__ eslist, float* __restrict__ agg_h0,
    float* __restrict__ agg_e) {
  int idx = blockIdx.x * 256 + threadIdx.x;
  int n = idx >> 5, k = idx & 31;
  if (n >= NN) return;
  int off = offs[n], dg = deg[n];
  float a0 = 0.f, a1 = 0.f, a2 = 0.f, a3 = 0.f;
  float h0 = 0.f, h1v = 0.f;
  int i = 0;
  for (; i + 8 <= dg; i += 8) {
    u64 p0 = eslist[off + i + 0], p1 = eslist[off + i + 1];
    u64 p2 = eslist[off + i + 2], p3 = eslist[off + i + 3];
    u64 p4 = eslist[off + i + 4], p5 = eslist[off + i + 5];
    u64 p6 = eslist[off + i + 6], p7 = eslist[off + i + 7];
    a0 += ea[(size_t)dec_e(p0) * 32 + k];
    a1 += ea[(size_t)dec_e(p1) * 32 + k];
    a2 += ea[(size_t)dec_e(p2) * 32 + k];
    a3 += ea[(size_t)dec_e(p3) * 32 + k];
    a0 += ea[(size_t)dec_e(p4) * 32 + k];
    a1 += ea[(size_t)dec_e(p5) * 32 + k];
    a2 += ea[(size_t)dec_e(p6) * 32 + k];
    a3 += ea[(size_t)dec_e(p7) * 32 + k];
    if (k < 2) {
      h0 += ns[(size_t)dec_s(p0) * 2 + k] + ns[(size_t)dec_s(p2) * 2 + k];
      h1v += ns[(size_t)dec_s(p1) * 2 + k] + ns[(size_t)dec_s(p3) * 2 + k];
      h0 += ns[(size_t)dec_s(p4) * 2 + k] + ns[(size_t)dec_s(p6) * 2 + k];
      h1v += ns[(size_t)dec_s(p5) * 2 + k] + ns[(size_t)dec_s(p7) * 2 + k];
    }
  }
  for (; i + 2 <= dg; i += 2) {
    u64 p0 = eslist[off + i], p1 = eslist[off + i + 1];
    a0 += ea[(size_t)dec_e(p0) * 32 + k];
    a1 += ea[(size_t)dec_e(p1) * 32 + k];
    if (k < 2) {
      h0 += ns[(size_t)dec_s(p0) * 2 + k];
      h1v += ns[(size_t)dec_s(p1) * 2 + k];
    }
  }
  if (i < dg) {
    u64 p0 = eslist[off + i];
    a0 += ea[(size_t)dec_e(p0) * 32 + k];
    if (k < 2) h0 += ns[(size_t)dec_s(p0) * 2 + k];
  }
  agg_e[(size_t)n * 32 + k] = (a0 + a1) + (a2 + a3);
  if (k < 2) agg_h0[(size_t)n * 2 + k] = h0 + h1v;
}

// ---------------- gather1: wave/node, 8-row unroll --------------------------
__global__ __launch_bounds__(256) void k_gather1(
    const __half* __restrict__ h1h, const int* __restrict__ offs,
    const int* __restrict__ deg, const u64* __restrict__ eslist,
    float* __restrict__ agg_h1) {
  int idx = blockIdx.x * 256 + threadIdx.x;
  int n = idx >> 6, lane = idx & 63;
  if (n >= NN) return;
  int off = offs[n], dg = deg[n];
  float a0 = 0.f, a1 = 0.f, a2 = 0.f, a3 = 0.f;
  int i = 0;
  for (; i + 8 <= dg; i += 8) {
    int s0 = dec_s(eslist[off + i + 0]), s1 = dec_s(eslist[off + i + 1]);
    int s2 = dec_s(eslist[off + i + 2]), s3 = dec_s(eslist[off + i + 3]);
    int s4 = dec_s(eslist[off + i + 4]), s5 = dec_s(eslist[off + i + 5]);
    int s6 = dec_s(eslist[off + i + 6]), s7 = dec_s(eslist[off + i + 7]);
    a0 += __half2float(h1h[(size_t)s0 * 64 + lane]);
    a1 += __half2float(h1h[(size_t)s1 * 64 + lane]);
    a2 += __half2float(h1h[(size_t)s2 * 64 + lane]);
    a3 += __half2float(h1h[(size_t)s3 * 64 + lane]);
    a0 += __half2float(h1h[(size_t)s4 * 64 + lane]);
    a1 += __half2float(h1h[(size_t)s5 * 64 + lane]);
    a2 += __half2float(h1h[(size_t)s6 * 64 + lane]);
    a3 += __half2float(h1h[(size_t)s7 * 64 + lane]);
  }
  for (; i + 2 <= dg; i += 2) {
    int s0 = dec_s(eslist[off + i]), s1 = dec_s(eslist[off + i + 1]);
    a0 += __half2float(h1h[(size_t)s0 * 64 + lane]);
    a1 += __half2float(h1h[(size_t)s1 * 64 + lane]);
  }
  if (i < dg) a0 += __half2float(h1h[(size_t)dec_s(eslist[off + i]) * 64 + lane]);
  agg_h1[(size_t)n * 64 + lane] = (a0 + a1) + (a2 + a3);
}

// ---------------- node linear 1 (vector; K=36) ------------------------------
__global__ __launch_bounds__(256) void k_node_lin1(
    const float* __restrict__ ns, const int* __restrict__ deg,
    const float* __restrict__ agg_h0, const float* __restrict__ agg_e,
    const float* __restrict__ W1t, const float* __restrict__ b1,
    __half* __restrict__ h1h) {
  int idx = blockIdx.x * 256 + threadIdx.x;
  int n = idx >> 6, o = idx & 63;
  if (n >= NN) return;
  float inv = 1.0f / fmaxf((float)deg[n], 1.0f);
  float acc = b1[o], acc2 = 0.f;
  acc += ns[n * 2 + 0] * W1t[0 * 64 + o] + ns[n * 2 + 1] * W1t[1 * 64 + o];
  acc2 += agg_h0[n * 2 + 0] * inv * W1t[2 * 64 + o] +
          agg_h0[n * 2 + 1] * inv * W1t[3 * 64 + o];
#pragma unroll
  for (int k = 0; k < 32; k += 2) {
    acc += agg_e[n * 32 + k] * inv * W1t[(4 + k) * 64 + o];
    acc2 += agg_e[n * 32 + k + 1] * inv * W1t[(5 + k) * 64 + o];
  }
  h1h[n * 64 + o] = __float2half(fmaxf(acc + acc2, 0.0f));
}

// ---------------- fused lin2 + pq: MFMA, 16-node tile per wave --------------
// NOTE: reads agg_e/agg_h1 BEFORE writing Pb/Qb which alias them. Each wave's
// task covers nodes [nb,nb+16): it reads agg rows only for those nodes and
// writes Pb/Qb rows only for those nodes. Pb@agg_e region: Pb row n occupies
// bytes n*128..n*128+127 of the region; agg_e row n occupies n*128.. same
// rows -> read-then-write within the SAME task, no cross-task hazard. Qb@
// agg_h1: Qb row n = bytes n*128.., agg_h1 row n = n*256.. -> Qb row n
// overlaps agg_h1 rows n/2 -- CROSS-TASK hazard! So Qb goes to agg_h1's
// UPPER half (@67NN = agg_h1 + 32NN units): agg_h1 rows 25000+ belong to
// tasks 1563+.. still cross-task. => keep Qb in h1h region instead: h1h is
// fully consumed by lin2pq stage-1 reads within the same task (rows nb..nb+15)
// -> same-row read-then-write, safe. Pb likewise over agg_e (same-row).
__global__ __launch_bounds__(256) void k_lin2pq(
    const __half* __restrict__ h1h, const int* __restrict__ deg,
    const float* __restrict__ agg_h1, const float* __restrict__ agg_e,
    const float* __restrict__ W2, const float* __restrict__ b2,
    const float* __restrict__ Wc1, const float* __restrict__ bc1,
    __half* __restrict__ Pb, __half* __restrict__ Qb) {
  __shared__ float Zt[4][16 * 68];
  int tid = threadIdx.x, lane = tid & 63, wid = tid >> 6;
  int col = lane & 15, quad = lane >> 4;
  float* zl = &Zt[wid][0];
  int task = blockIdx.x * 4 + wid;
  if (task >= NN / 16) return;  // NN = 3125*16 exactly
  int nb = task * 16;
  int nrow = nb + col;
  float inv = 1.0f / fmaxf((float)deg[nrow], 1.0f);

  f32x4 zero = {0.f, 0.f, 0.f, 0.f};
  f32x4 ce[4] = {zero, zero, zero, zero};

#pragma unroll
  for (int kc = 0; kc < 5; ++kc) {
    f16x8 af;
    if (kc < 2) {
      U4 u;
      u.u = *(const uint4*)(h1h + (size_t)nrow * 64 + kc * 32 + quad * 8);
      af = u.f;
    } else if (kc < 4) {
      const float* p = agg_h1 + (size_t)nrow * 64 + (kc - 2) * 32 + quad * 8;
      float4 a0 = ((const float4*)p)[0], a1 = ((const float4*)p)[1];
      a0.x *= inv; a0.y *= inv; a0.z *= inv; a0.w *= inv;
      a1.x *= inv; a1.y *= inv; a1.z *= inv; a1.w *= inv;
      af = cvt8(a0, a1);
    } else {
      const float* p = agg_e + (size_t)nrow * 32 + quad * 8;
      float4 a0 = ((const float4*)p)[0], a1 = ((const float4*)p)[1];
      a0.x *= inv; a0.y *= inv; a0.z *= inv; a0.w *= inv;
      a1.x *= inv; a1.y *= inv; a1.z *= inv; a1.w *= inv;
      af = cvt8(a0, a1);
    }
#pragma unroll
    for (int ob = 0; ob < 4; ++ob) {
      const float* wp = W2 + (size_t)(ob * 16 + col) * 160 + kc * 32 + quad * 8;
      f16x8 bf = cvt8(((const float4*)wp)[0], ((const float4*)wp)[1]);
      ce[ob] = __builtin_amdgcn_mfma_f32_16x16x32_f16(af, bf, ce[ob], 0, 0, 0);
    }
  }
#pragma unroll
  for (int ob = 0; ob < 4; ++ob) {
    float bv = b2[ob * 16 + col];
#pragma unroll
    for (int j = 0; j < 4; ++j)
      zl[(quad * 4 + j) * 68 + ob * 16 + col] = fmaxf(ce[ob][j] + bv, 0.f);
  }

  f32x4 pacc[4] = {zero, zero, zero, zero};
  f32x4 qacc[4] = {zero, zero, zero, zero};
#pragma unroll
  for (int kc = 0; kc < 2; ++kc) {
    const float* zc = zl + col * 68 + kc * 32 + quad * 8;
    f16x8 az = cvt8(((const float4*)zc)[0], ((const float4*)zc)[1]);
#pragma unroll
    for (int ob = 0; ob < 4; ++ob) {
      const float* wa = Wc1 + (size_t)(ob * 16 + col) * 160 + kc * 32 + quad * 8;
      f16x8 ba = cvt8(((const float4*)wa)[0], ((const float4*)wa)[1]);
      pacc[ob] = __builtin_amdgcn_mfma_f32_16x16x32_f16(az, ba, pacc[ob], 0, 0, 0);
      const float* wb = wa + 64;
      f16x8 bb = cvt8(((const float4*)wb)[0], ((const float4*)wb)[1]);
      qacc[ob] = __builtin_amdgcn_mfma_f32_16x16x32_f16(az, bb, qacc[ob], 0, 0, 0);
    }
  }
  __syncthreads();  // ensure all stage-1/2 reads in this block precede writes
#pragma unroll
  for (int ob = 0; ob < 4; ++ob) {
    float bv = bc1[ob * 16 + col];
#pragma unroll
    for (int j = 0; j < 4; ++j) {
      int n = nb + quad * 4 + j;
      Pb[(size_t)n * 64 + ob * 16 + col] = __float2half(pacc[ob][j] + bv);
      Qb[(size_t)n * 64 + ob * 16 + col] = __float2half(qacc[ob][j]);
    }
  }
}

// ---------------- edge classifier: MFMA, CSR order (d sorted) ---------------
#define CLS_BLOCKS 3125  // 12500 waves, 1 task (64 CSR slots) each
__global__ __launch_bounds__(256, 4) void k_edge_cls(
    const u64* __restrict__ eslist, const float* __restrict__ ea,
    const __half* __restrict__ Pb, const __half* __restrict__ Qb,
    const float* __restrict__ Wc1, const float* __restrict__ Wc2,
    const float* __restrict__ bc2, const float* __restrict__ Wc3,
    const float* __restrict__ bc3, float* __restrict__ out) {
  __shared__ float Zt[4][16 * 68];  // single buffer: 17408 B
  int tid = threadIdx.x;
  int lane = tid & 63, wid = tid >> 6;
  int col = lane & 15, quad = lane >> 4;
  float* zl = &Zt[wid][0];

  f16x8 ctF[4];
#pragma unroll
  for (int nt = 0; nt < 4; ++nt) {
    const float* p = Wc1 + (nt * 16 + col) * 160 + 128 + quad * 8;
    ctF[nt] = cvt8(((const float4*)p)[0], ((const float4*)p)[1]);
  }
  f16x8 w2F[2][2];
#pragma unroll
  for (int nt = 0; nt < 2; ++nt)
#pragma unroll
    for (int ks = 0; ks < 2; ++ks) {
      const float* p = Wc2 + (nt * 16 + col) * 64 + ks * 32 + quad * 8;
      w2F[nt][ks] = cvt8(((const float4*)p)[0], ((const float4*)p)[1]);
    }
  float wc3v0 = Wc3[col], wc3v1 = Wc3[16 + col];
  float bc2v0 = bc2[col], bc2v1 = bc2[16 + col];
  float bc3v = bc3[0];

  int gw = blockIdx.x * 4 + wid;
  for (int task = gw; task < NE / 64; task += CLS_BLOCKS * 4) {
    int tb = task * 64;
    // hoist all 4 tiles' slot loads (coalesced 128B per 16 lanes)
    u64 vArr[4];
#pragma unroll
    for (int mt = 0; mt < 4; ++mt) vArr[mt] = eslist[tb + mt * 16 + col];
#pragma unroll
    for (int mt = 0; mt < 4; ++mt) {
      u64 v = vArr[mt];
      int e = dec_e(v), s = dec_s(v), d = dec_d(v);

      const float* eap = ea + (size_t)e * 32 + quad * 8;
      f16x8 ua = cvt8(((const float4*)eap)[0], ((const float4*)eap)[1]);
      f32x4 zero = {0.f, 0.f, 0.f, 0.f};
      f32x4 ce[4];
#pragma unroll
      for (int nt = 0; nt < 4; ++nt)
        ce[nt] = __builtin_amdgcn_mfma_f32_16x16x32_f16(ua, ctF[nt], zero,
                                                        0, 0, 0);
#pragma unroll
      for (int nt = 0; nt < 4; ++nt)
#pragma unroll
        for (int j = 0; j < 4; ++j)
          zl[(quad * 4 + j) * 68 + nt * 16 + col] = ce[nt][j];

      const __half* prow = Pb + (size_t)s * 64 + quad * 8;
      const __half* qrow = Qb + (size_t)d * 64 + quad * 8;  // d sorted: hits
      f32x4 tacc0 = zero, tacc1 = zero;
#pragma unroll
      for (int ks = 0; ks < 2; ++ks) {
        U4 up, uq;
        up.u = *(const uint4*)(prow + ks * 32);
        uq.u = *(const uint4*)(qrow + ks * 32);
        const float* zc = zl + col * 68 + ks * 32 + quad * 8;
        float4 c0 = *(const float4*)(zc);
        float4 c1 = *(const float4*)(zc + 4);
        U4 uz;
        {
          float2 pf, qf;
          pf = __half22float2(up.h2[0]); qf = __half22float2(uq.h2[0]);
          uz.h2[0] = __floats2half2_rn(fmaxf(pf.x + qf.x + c0.x, 0.f),
                                       fmaxf(pf.y + qf.y + c0.y, 0.f));
          pf = __half22float2(up.h2[1]); qf = __half22float2(uq.h2[1]);
          uz.h2[1] = __floats2half2_rn(fmaxf(pf.x + qf.x + c0.z, 0.f),
                                       fmaxf(pf.y + qf.y + c0.w, 0.f));
          pf = __half22float2(up.h2[2]); qf = __half22float2(uq.h2[2]);
          uz.h2[2] = __floats2half2_rn(fmaxf(pf.x + qf.x + c1.x, 0.f),
                                       fmaxf(pf.y + qf.y + c1.y, 0.f));
          pf = __half22float2(up.h2[3]); qf = __half22float2(uq.h2[3]);
          uz.h2[3] = __floats2half2_rn(fmaxf(pf.x + qf.x + c1.z, 0.f),
                                       fmaxf(pf.y + qf.y + c1.w, 0.f));
        }
        tacc0 = __builtin_amdgcn_mfma_f32_16x16x32_f16(uz.f, w2F[0][ks],
                                                       tacc0, 0, 0, 0);
        tacc1 = __builtin_amdgcn_mfma_f32_16x16x32_f16(uz.f, w2F[1][ks],
                                                       tacc1, 0, 0, 0);
      }

      float vj[4];
#pragma unroll
      for (int j = 0; j < 4; ++j) {
        float t0 = fmaxf(tacc0[j] + bc2v0, 0.f);
        float t1 = fmaxf(tacc1[j] + bc2v1, 0.f);
        vj[j] = t0 * wc3v0 + t1 * wc3v1;
      }
#pragma unroll
      for (int m = 1; m < 16; m <<= 1) {
#pragma unroll
        for (int j = 0; j < 4; ++j) vj[j] += __shfl_xor(vj[j], m);
      }
      // each output row's e lives in lane (any quad, col = quad*4+j):
      int ej[4];
#pragma unroll
      for (int j = 0; j < 4; ++j) ej[j] = __shfl(e, quad * 4 + j);
      if (col == 0) {
#pragma unroll
        for (int j = 0; j < 4; ++j) out[ej[j]] = vj[j] + bc3v;
      }
    }
  }
}

extern "C" void kernel_launch(void* const* d_in, const int* in_sizes, int n_in,
                              void* d_out, int out_size, void* d_ws, size_t ws_size,
                              hipStream_t stream) {
  const int*   ei  = (const int*)d_in[1];
  const float* ea  = (const float*)d_in[2];
  const float* ns  = (const float*)d_in[3];
  const float* W1  = (const float*)d_in[4];
  const float* b1  = (const float*)d_in[5];
  const float* W2  = (const float*)d_in[6];
  const float* b2  = (const float*)d_in[7];
  const float* Wc1 = (const float*)d_in[8];
  const float* bc1 = (const float*)d_in[9];
  const float* Wc2 = (const float*)d_in[10];
  const float* bc2 = (const float*)d_in[11];
  const float* Wc3 = (const float*)d_in[12];
  const float* bc3 = (const float*)d_in[13];
  float* out = (float*)d_out;

  float*  ws     = (float*)d_ws;
  int*    deg    = (int*)ws;
  float*  agg_h0 = ws + (size_t)NN;
  float*  agg_e  = ws + (size_t)3 * NN;
  float*  agg_h1 = ws + (size_t)35 * NN;
  __half* h1h    = (__half*)(ws + (size_t)99 * NN);
  float*  W1t    = ws + (size_t)131 * NN;
  int*    bsums  = (int*)(W1t + 30000);
  int*    offs   = (int*)(ws + (size_t)132 * NN);
  int*    fill   = (int*)(ws + (size_t)133 * NN);
  u64*    eslist = (u64*)(ws + (size_t)134 * NN);    // 32NN units -> 166NN
  // Pb over agg_e (rows align 1:1 per node), Qb over h1h (rows align 1:1):
  // both are read-then-written for the SAME node rows inside k_lin2pq tasks,
  // and dead (as agg/h1) afterwards. eslist stays fully intact for cls.
  __half* Pb     = (__half*)(ws + (size_t)3 * NN);   // 32NN units (over agg_e)
  __half* Qb     = (__half*)(ws + (size_t)99 * NN);  // 32NN units (over h1h)

  hipMemsetAsync(deg, 0, NN * sizeof(int), stream);

  k_hist<<<NB_HIST + 9, 256, 0, stream>>>(ei, deg, W1, W1t);
  k_scan1<<<NB_SCAN, 256, 0, stream>>>(deg, offs, bsums);
  k_scan2<<<1, 256, 0, stream>>>(bsums);
  k_scan3<<<NB_SCAN, 256, 0, stream>>>(offs, bsums, fill);
  k_scatter<<<NB_HIST, 256, 0, stream>>>(ei, fill, eslist);

  k_gather0<<<(NN * 32 + 255) / 256, 256, 0, stream>>>(ea, ns, offs, deg,
                                                       eslist, agg_h0, agg_e);
  k_node_lin1<<<(NN * 64 + 255) / 256, 256, 0, stream>>>(ns, deg, agg_h0,
                                                         agg_e, W1t, b1, h1h);
  k_gather1<<<(NN * 64 + 255) / 256, 256, 0, stream>>>(h1h, offs, deg, eslist,
                                                       agg_h1);
  k_lin2pq<<<(NN / 16 + 3) / 4, 256, 0, stream>>>(h1h, deg, agg_h1, agg_e, W2,
                                                  b2, Wc1, bc1, Pb, Qb);
  k_edge_cls<<<CLS_BLOCKS, 256, 0, stream>>>(eslist, ea, Pb, Qb, Wc1, Wc2,
                                             bc2, Wc3, bc3, out);
}